// Round 1
// baseline (97.674 us; speedup 1.0000x reference)
//
#include <hip/hip_runtime.h>
#include <math.h>

#define Bb 8
#define Nn 4096
#define Mm 4096

// accum layout in d_ws (4 floats):
// [0] = sum over (b,n) of min_m d2      (chamfer dir A)
// [1] = sum over (b,n) of sqrt(min_m d2) (emd)
// [2] = sum over (b,m) of min_n d2      (chamfer dir B)
// [3] = sum of uncertainty

// One block = 256 threads = 4 waves. Block covers 64 "query" points of one
// batch; each wave scans a quarter of the Mp "target" points. Target loads
// are wave-uniform (base hoisted to SGPR via readfirstlane) -> s_load on the
// SMEM pipe, keeping the VALU free for the distance math.
__global__ void __launch_bounds__(256) dir_min_kernel(
    const float* __restrict__ P,   // [Bb, Np, 3] query points
    const float* __restrict__ T,   // [Bb, Mp, 3] target points
    int Np, int Mp,
    float* __restrict__ accum, int accIdx, int doEmd)
{
    const int tid  = threadIdx.x;
    const int lane = tid & 63;
    const int wave = tid >> 6;
    const int blocksPerBatch = Np >> 6;          // Np / 64
    const int b    = blockIdx.x / blocksPerBatch;
    const int tile = blockIdx.x % blocksPerBatch;
    const int n    = (tile << 6) + lane;

    const float* p = P + ((size_t)b * Np + n) * 3;
    const float px = p[0], py = p[1], pz = p[2];

    const int mlen = Mp >> 2;                    // quarter per wave
    const int mbase = __builtin_amdgcn_readfirstlane(wave * mlen);
    const float* tb = T + ((size_t)b * Mp + mbase) * 3;

    // 4 independent min accumulators to break the fminf dependency chain
    float mn0 = __builtin_inff(), mn1 = mn0, mn2 = mn0, mn3 = mn0;
    for (int m = 0; m < mlen; m += 4) {
        const float* q = tb + 3 * m;
        float dx, dy, dz, d2;
        dx = px - q[0];  dy = py - q[1];  dz = pz - q[2];
        d2 = fmaf(dx, dx, fmaf(dy, dy, dz * dz));  mn0 = fminf(mn0, d2);
        dx = px - q[3];  dy = py - q[4];  dz = pz - q[5];
        d2 = fmaf(dx, dx, fmaf(dy, dy, dz * dz));  mn1 = fminf(mn1, d2);
        dx = px - q[6];  dy = py - q[7];  dz = pz - q[8];
        d2 = fmaf(dx, dx, fmaf(dy, dy, dz * dz));  mn2 = fminf(mn2, d2);
        dx = px - q[9];  dy = py - q[10]; dz = pz - q[11];
        d2 = fmaf(dx, dx, fmaf(dy, dy, dz * dz));  mn3 = fminf(mn3, d2);
    }
    float mn = fminf(fminf(mn0, mn1), fminf(mn2, mn3));

    __shared__ float smin[4][64];
    smin[wave][lane] = mn;
    __syncthreads();

    if (wave == 0) {
        float v = fminf(fminf(smin[0][lane], smin[1][lane]),
                        fminf(smin[2][lane], smin[3][lane]));
        float s1 = v;
        float s2 = doEmd ? sqrtf(fmaxf(v, 0.0f)) : 0.0f;
        #pragma unroll
        for (int off = 32; off > 0; off >>= 1) {
            s1 += __shfl_down(s1, off);
            s2 += __shfl_down(s2, off);
        }
        if (lane == 0) {
            atomicAdd(&accum[accIdx], s1);
            if (doEmd) atomicAdd(&accum[1], s2);
        }
    }
}

__global__ void __launch_bounds__(256) unc_reduce_kernel(
    const float* __restrict__ u, int total, float* __restrict__ accum)
{
    float s = 0.0f;
    for (int i = blockIdx.x * blockDim.x + threadIdx.x; i < total;
         i += gridDim.x * blockDim.x)
        s += u[i];
    #pragma unroll
    for (int off = 32; off > 0; off >>= 1)
        s += __shfl_down(s, off);
    __shared__ float sw[4];
    const int lane = threadIdx.x & 63, wave = threadIdx.x >> 6;
    if (lane == 0) sw[wave] = s;
    __syncthreads();
    if (threadIdx.x == 0)
        atomicAdd(&accum[3], sw[0] + sw[1] + sw[2] + sw[3]);
}

__global__ void finalize_kernel(const float* __restrict__ accum,
                                float* __restrict__ out)
{
    if (threadIdx.x == 0 && blockIdx.x == 0) {
        const float invBN = 1.0f / (float)(Bb * Nn);
        const float invBM = 1.0f / (float)(Bb * Mm);
        const float chamfer = accum[0] * invBN + accum[2] * invBM;
        const float emd     = accum[1] * invBN;
        const float uncm    = accum[3] * invBN;
        out[0] = chamfer * 1.0f + emd * 0.5f + uncm * 0.01f;
    }
}

extern "C" void kernel_launch(void* const* d_in, const int* in_sizes, int n_in,
                              void* d_out, int out_size, void* d_ws, size_t ws_size,
                              hipStream_t stream) {
    const float* pred = (const float*)d_in[0];   // [8,4096,3]
    const float* targ = (const float*)d_in[1];   // [8,4096,3]
    const float* unc  = (const float*)d_in[2];   // [8,4096]
    float* out = (float*)d_out;
    float* accum = (float*)d_ws;

    hipMemsetAsync(accum, 0, 4 * sizeof(float), stream);

    const int blocksA = Bb * (Nn >> 6);   // 512
    const int blocksB = Bb * (Mm >> 6);   // 512
    // direction A: per pred point, min over targets (chamfer + emd)
    dir_min_kernel<<<blocksA, 256, 0, stream>>>(pred, targ, Nn, Mm, accum, 0, 1);
    // direction B: per target point, min over preds (chamfer only)
    dir_min_kernel<<<blocksB, 256, 0, stream>>>(targ, pred, Mm, Nn, accum, 2, 0);

    unc_reduce_kernel<<<32, 256, 0, stream>>>(unc, Bb * Nn, accum);
    finalize_kernel<<<1, 64, 0, stream>>>(accum, out);
}

// Round 2
// 56.158 us; speedup vs baseline: 1.7393x; 1.7393x over previous
//
#include <hip/hip_runtime.h>
#include <math.h>

#define Bb 8
#define Nn 4096
#define Mm 4096
#define QP 4                 // query points per thread (in registers)
#define WAVES 8              // waves per block; each wave scans Mm/WAVES targets
#define BLOCK (WAVES * 64)   // 512 threads
#define SLICE (Mm / WAVES)   // 512 targets per wave

// accum layout in d_ws (4 floats):
// [0] = sum over (b,n) of min_m d2       (chamfer dir A)
// [1] = sum over (b,n) of sqrt(min_m d2) (emd)
// [2] = sum over (b,m) of min_n d2       (chamfer dir B)

// One dispatch covers BOTH directions (dir = blockIdx.x>>7).
// Block: 512 threads = 8 waves, covers 256 query points (64 lanes x QP),
// stages ALL 4096 targets of its batch into LDS as float4(x,y,z,|t|^2),
// then wave w scans target slice [w*512, (w+1)*512) using the expansion
//   d2 = |p|^2 + (|t|^2 - 2 p.t)
// -> per (query,target): 3 FMA + 1 min, |p|^2 added once after the min.
__global__ void __launch_bounds__(BLOCK) chamfer_kernel(
    const float* __restrict__ pred,
    const float* __restrict__ targ,
    float* __restrict__ accum)
{
    __shared__ float4 ts[Mm];          // 64 KB; reused as smin after main loop

    const int tid  = threadIdx.x;
    const int lane = tid & 63;
    const int wave = tid >> 6;

    const int dir  = blockIdx.x >> 7;  // 0: pred->targ (chamferA+emd), 1: targ->pred
    const int bb   = blockIdx.x & 127;
    const int b    = bb >> 4;          // 16 blocks per batch
    const int tile = bb & 15;

    const float* Q = (dir == 0) ? pred : targ;
    const float* T = (dir == 0) ? targ : pred;

    // ---- stage targets: coalesced global read, compute |t|^2 once ----
    for (int i = tid; i < Mm; i += BLOCK) {
        const float* g = T + ((size_t)b * Mm + i) * 3;
        float x = g[0], y = g[1], z = g[2];
        ts[i] = make_float4(x, y, z, fmaf(x, x, fmaf(y, y, z * z)));
    }

    // ---- load this thread's QP query points into registers ----
    float npx[QP], npy[QP], npz[QP], pp[QP], mn[QP];
    #pragma unroll
    for (int q = 0; q < QP; ++q) {
        const int n = tile * (64 * QP) + q * 64 + lane;
        const float* g = Q + ((size_t)b * Nn + n) * 3;
        float x = g[0], y = g[1], z = g[2];
        npx[q] = -2.0f * x;
        npy[q] = -2.0f * y;
        npz[q] = -2.0f * z;
        pp[q]  = fmaf(x, x, fmaf(y, y, z * z));
        mn[q]  = __builtin_inff();
    }

    __syncthreads();

    // ---- main loop: 1 broadcast ds_read_b128 + 16 VALU per target ----
    const float4* tw = ts + (wave * SLICE);
    #pragma unroll 4
    for (int m = 0; m < SLICE; ++m) {
        const float4 t = tw[m];
        #pragma unroll
        for (int q = 0; q < QP; ++q) {
            float d = fmaf(npx[q], t.x, fmaf(npy[q], t.y, fmaf(npz[q], t.z, t.w)));
            mn[q] = fminf(mn[q], d);
        }
    }

    __syncthreads();                       // done reading ts -> reuse as smin
    float* smin = (float*)ts;              // [QP][WAVES][64]
    #pragma unroll
    for (int q = 0; q < QP; ++q)
        smin[(q * WAVES + wave) * 64 + lane] = mn[q];
    __syncthreads();

    // ---- cross-wave min combine + block sum + atomic ----
    if (wave < QP) {
        const int q = wave;                // wave q reduces query row q (it holds pp[q])
        float v = __builtin_inff();
        #pragma unroll
        for (int w = 0; w < WAVES; ++w)
            v = fminf(v, smin[(q * WAVES + w) * 64 + lane]);
        const float d2 = pp[q] + v;
        float s1 = d2;
        float s2 = (dir == 0) ? sqrtf(fmaxf(d2, 0.0f)) : 0.0f;
        #pragma unroll
        for (int off = 32; off > 0; off >>= 1) {
            s1 += __shfl_down(s1, off);
            s2 += __shfl_down(s2, off);
        }
        if (lane == 0) {
            atomicAdd(&accum[(dir == 0) ? 0 : 2], s1);
            if (dir == 0) atomicAdd(&accum[1], s2);
        }
    }
}

// uncertainty mean + final combine, one small block (runs after chamfer_kernel
// in stream order)
__global__ void __launch_bounds__(1024) finalize_kernel(
    const float* __restrict__ u, const float* __restrict__ accum,
    float* __restrict__ out)
{
    float s = 0.0f;
    for (int i = threadIdx.x; i < Bb * Nn; i += 1024)
        s += u[i];
    #pragma unroll
    for (int off = 32; off > 0; off >>= 1)
        s += __shfl_down(s, off);
    __shared__ float sw[16];
    const int lane = threadIdx.x & 63, wave = threadIdx.x >> 6;
    if (lane == 0) sw[wave] = s;
    __syncthreads();
    if (threadIdx.x == 0) {
        float su = 0.0f;
        #pragma unroll
        for (int w = 0; w < 16; ++w) su += sw[w];
        const float invBN = 1.0f / (float)(Bb * Nn);
        const float invBM = 1.0f / (float)(Bb * Mm);
        const float chamfer = accum[0] * invBN + accum[2] * invBM;
        const float emd     = accum[1] * invBN;
        out[0] = chamfer + 0.5f * emd + 0.01f * (su * invBN);
    }
}

extern "C" void kernel_launch(void* const* d_in, const int* in_sizes, int n_in,
                              void* d_out, int out_size, void* d_ws, size_t ws_size,
                              hipStream_t stream) {
    const float* pred = (const float*)d_in[0];   // [8,4096,3]
    const float* targ = (const float*)d_in[1];   // [8,4096,3]
    const float* unc  = (const float*)d_in[2];   // [8,4096]
    float* out   = (float*)d_out;
    float* accum = (float*)d_ws;

    hipMemsetAsync(accum, 0, 4 * sizeof(float), stream);

    // 2 dirs x 8 batches x 16 tiles = 256 blocks of 512 threads
    chamfer_kernel<<<256, BLOCK, 0, stream>>>(pred, targ, accum);
    finalize_kernel<<<1, 1024, 0, stream>>>(unc, accum, out);
}

// Round 3
// 36.553 us; speedup vs baseline: 2.6721x; 1.5363x over previous
//
#include <hip/hip_runtime.h>
#include <math.h>

#define Bb 8
#define Nn 4096
#define Mm 4096
#define QP 4                   // query points per thread (registers)
#define WAVES 8                // waves per block
#define BLOCK (WAVES * 64)     // 512 threads
#define MH (Mm / 2)            // 2048 targets per M-half (32 KB LDS)
#define SLICE (MH / WAVES)     // 256 targets per wave
#define QTILES (Nn / (64 * QP))// 16 query tiles per (dir,b)
#define NQ_TOTAL (2 * Bb * Nn) // 65536 query slots (both dirs)

// d_ws layout:
//   [0..3]                : accum  {chamferA_sum, emd_sum, chamferB_sum, unc_sum}
//   [4 .. 4+2*NQ_TOTAL)   : per-query per-half partial mins (pp + min_half)

// grid = 2 dirs x 8 batches x 16 qtiles x 2 halves = 512 blocks of 512 thr.
// 32 KB LDS/block -> 2 blocks/CU -> 16 waves/CU (4/SIMD) for latency hiding.
__global__ void __launch_bounds__(BLOCK) chamfer_kernel(
    const float* __restrict__ pred,
    const float* __restrict__ targ,
    float* __restrict__ mins)
{
    __shared__ float4 ts[MH + 8];      // +8 pad for the prefetch pipeline

    const int tid  = threadIdx.x;
    const int lane = tid & 63;
    const int wave = tid >> 6;

    const int id   = blockIdx.x;
    const int half = id & 1;
    const int tile = (id >> 1) & (QTILES - 1);
    const int b    = (id >> 5) & (Bb - 1);
    const int dir  = id >> 8;

    const float* Q = dir ? targ : pred;
    const float* T = dir ? pred : targ;

    // ---- stage this M-half: float4(x,y,z,|t|^2) ----
    for (int i = tid; i < MH; i += BLOCK) {
        const float* g = T + ((size_t)b * Mm + half * MH + i) * 3;
        float x = g[0], y = g[1], z = g[2];
        ts[i] = make_float4(x, y, z, fmaf(x, x, fmaf(y, y, z * z)));
    }
    if (tid < 8) ts[MH + tid] = make_float4(0.f, 0.f, 0.f, __builtin_inff());

    // ---- this thread's QP query points ----
    float npx[QP], npy[QP], npz[QP], pp[QP], mn[QP];
    #pragma unroll
    for (int q = 0; q < QP; ++q) {
        const int n = tile * (64 * QP) + q * 64 + lane;
        const float* g = Q + ((size_t)b * Nn + n) * 3;
        float x = g[0], y = g[1], z = g[2];
        npx[q] = -2.0f * x;  npy[q] = -2.0f * y;  npz[q] = -2.0f * z;
        pp[q]  = fmaf(x, x, fmaf(y, y, z * z));
        mn[q]  = __builtin_inff();
    }

    __syncthreads();

    // ---- main loop: 4-deep register pipeline over this wave's slice ----
    const float4* tw = ts + wave * SLICE;
    float4 t0 = tw[0], t1 = tw[1], t2 = tw[2], t3 = tw[3];
    for (int m = 0; m < SLICE; m += 4) {
        float4 u0 = tw[m + 4], u1 = tw[m + 5], u2 = tw[m + 6], u3 = tw[m + 7];
        #pragma unroll
        for (int q = 0; q < QP; ++q) {
            float dA = fmaf(npx[q], t0.x, fmaf(npy[q], t0.y, fmaf(npz[q], t0.z, t0.w)));
            float dB = fmaf(npx[q], t1.x, fmaf(npy[q], t1.y, fmaf(npz[q], t1.z, t1.w)));
            mn[q] = fminf(fminf(mn[q], dA), dB);          // -> v_min3_f32
            float dC = fmaf(npx[q], t2.x, fmaf(npy[q], t2.y, fmaf(npz[q], t2.z, t2.w)));
            float dD = fmaf(npx[q], t3.x, fmaf(npy[q], t3.y, fmaf(npz[q], t3.z, t3.w)));
            mn[q] = fminf(fminf(mn[q], dC), dD);          // -> v_min3_f32
        }
        t0 = u0; t1 = u1; t2 = u2; t3 = u3;
    }

    __syncthreads();                    // done reading ts -> reuse as smin
    float* smin = (float*)ts;           // [QP][WAVES][64]
    #pragma unroll
    for (int q = 0; q < QP; ++q)
        smin[(q * WAVES + wave) * 64 + lane] = mn[q];
    __syncthreads();

    // ---- cross-wave min, write partial (pp + min) to d_ws ----
    if (wave < QP) {
        const int q = wave;             // n is wave-independent, pp[q] valid here
        float v = __builtin_inff();
        #pragma unroll
        for (int w = 0; w < WAVES; ++w)
            v = fminf(v, smin[(q * WAVES + w) * 64 + lane]);
        const int n = tile * (64 * QP) + q * 64 + lane;
        const size_t qg = ((size_t)dir * Bb + b) * Nn + n;
        mins[qg * 2 + half] = pp[q] + v;
    }
}

// combine halves, accumulate chamfer/emd/unc sums via per-block atomics
__global__ void __launch_bounds__(256) reduce_kernel(
    const float* __restrict__ mins, const float* __restrict__ unc,
    float* __restrict__ accum)
{
    const int gid = blockIdx.x * 256 + threadIdx.x;   // grid covers 32768
    float sA = 0.f, sE = 0.f, sB = 0.f, sU = 0.f;
    #pragma unroll
    for (int k = 0; k < 2; ++k) {                     // queries gid, gid+32768
        const int i = gid + k * 32768;
        const float v = fminf(mins[2 * i], mins[2 * i + 1]);
        if (k == 0) { sA = v; sE = sqrtf(fmaxf(v, 0.f)); }
        else        { sB = v; }
    }
    sU = unc[gid];

    #pragma unroll
    for (int off = 32; off > 0; off >>= 1) {
        sA += __shfl_down(sA, off);  sE += __shfl_down(sE, off);
        sB += __shfl_down(sB, off);  sU += __shfl_down(sU, off);
    }
    __shared__ float sw[4][4];
    const int lane = threadIdx.x & 63, wave = threadIdx.x >> 6;
    if (lane == 0) { sw[wave][0] = sA; sw[wave][1] = sE; sw[wave][2] = sB; sw[wave][3] = sU; }
    __syncthreads();
    if (threadIdx.x < 4) {
        float s = sw[0][threadIdx.x] + sw[1][threadIdx.x] + sw[2][threadIdx.x] + sw[3][threadIdx.x];
        atomicAdd(&accum[threadIdx.x], s);
    }
}

__global__ void finalize_kernel(const float* __restrict__ accum,
                                float* __restrict__ out)
{
    if (threadIdx.x == 0) {
        const float invBN = 1.0f / (float)(Bb * Nn);
        const float invBM = 1.0f / (float)(Bb * Mm);
        const float chamfer = accum[0] * invBN + accum[2] * invBM;
        const float emd     = accum[1] * invBN;
        const float uncm    = accum[3] * invBN;
        out[0] = chamfer + 0.5f * emd + 0.01f * uncm;
    }
}

extern "C" void kernel_launch(void* const* d_in, const int* in_sizes, int n_in,
                              void* d_out, int out_size, void* d_ws, size_t ws_size,
                              hipStream_t stream) {
    const float* pred = (const float*)d_in[0];   // [8,4096,3]
    const float* targ = (const float*)d_in[1];   // [8,4096,3]
    const float* unc  = (const float*)d_in[2];   // [8,4096]
    float* out   = (float*)d_out;
    float* accum = (float*)d_ws;
    float* mins  = (float*)d_ws + 4;

    hipMemsetAsync(accum, 0, 4 * sizeof(float), stream);

    chamfer_kernel<<<512, BLOCK, 0, stream>>>(pred, targ, mins);
    reduce_kernel<<<128, 256, 0, stream>>>(mins, unc, accum);
    finalize_kernel<<<1, 64, 0, stream>>>(accum, out);
}